// Round 5
// baseline (61.465 us; speedup 1.0000x reference)
//
#include <hip/hip_runtime.h>

#define NCLS 256

typedef float f32x4_t __attribute__((ext_vector_type(4)));

// DPP partial-sum helpers (verified in rounds 2-4).
#define DPP_ADD(x, ctrl) \
    ((x) + __int_as_float(__builtin_amdgcn_update_dpp( \
        0, __float_as_int(x), (ctrl), 0xF, 0xF, true)))

__device__ __forceinline__ float red16(float x) {
    x = DPP_ADD(x, 0xB1);   // quad_perm xor1
    x = DPP_ADD(x, 0x4E);   // quad_perm xor2
    x = DPP_ADD(x, 0x141);  // row_half_mirror
    x = DPP_ADD(x, 0x140);  // row_mirror
    return x;
}

__device__ __forceinline__ float red64(float x) {
    x = red16(x);
    x += __shfl_xor(x, 16);
    x += __shfl_xor(x, 32);
    return x;               // all lanes hold the wave sum
}

// Per-row closed form (no max-subtraction; logits ~ N(0,1) so exp is safe):
//   lrow = A[t] + log(sum_c exp(x_c)) - swx * invS[t]
// A[t], invS[t]: t-only -> LDS table (t is wave-uniform here -> broadcast).
// The swx*invS term is LINEAR in lane partials -> accumulate per-lane across
// all rows (accW), reduce ONCE at the end. A[t]+log z is wave-uniform ->
// accumulate identically on all lanes (accU), divide by 64 in the final sum.
// Memory pattern: each wave load = one contiguous 1 KiB row (lane-linear),
// 4 consecutive rows per chunk — same shape as the 6.3-6.9 TB/s streams.
__global__ __launch_bounds__(256) void SmoothOrdinalLoss_kernel(
    const float* __restrict__ logits,
    const int* __restrict__ targets,
    float* __restrict__ out,
    int batch)
{
    __shared__ float2 ab[NCLS];
    __shared__ float  part[4];

    const int tid = threadIdx.x;

    // ---- build A/invS table (once per block; tid == class t) ----
    {
        const int t = tid;
        float sw = 0.0f, swlw = 0.0f;
        #pragma unroll
        for (int d = -8; d <= 8; ++d) {
            int c = t + d;
            if (c >= 0 && c < NCLS) {
                float fd = (float)d;
                float a  = (fd * fd) * (fd * fd) * 0.02f;  // d^4/50
                float w  = __expf(-a);
                sw += w;
                swlw = fmaf(w, -a, swlw);                  // w * log w
            }
        }
        float invS = 1.0f / sw;
        ab[t] = make_float2(fmaf(swlw, invS, -__logf(sw)), invS);
    }
    __syncthreads();

    const int lane = tid & 63;
    const int wib  = tid >> 6;

    const int wave    = blockIdx.x * 4 + wib;
    const int nwaves  = gridDim.x * 4;
    const int nchunks = batch >> 2;          // 4 consecutive rows per chunk

    float accW = 0.0f;   // -sum swx*invS   (per-lane partial, reduced at end)
    float accU = 0.0f;   // sum A[t]+log z  (identical on all lanes)

    const float fl4 = (float)(4 * lane);

    for (int ch = wave; ch < nchunks; ch += nwaves) {
        const int rbase = ch * 4;
        const float* bp = logits + (size_t)rbase * NCLS;
        // 4 loads, each 64 lanes x 16 B = 1 KiB fully contiguous.
        f32x4_t v0 = reinterpret_cast<const f32x4_t*>(bp)[lane];
        f32x4_t v1 = reinterpret_cast<const f32x4_t*>(bp + NCLS)[lane];
        f32x4_t v2 = reinterpret_cast<const f32x4_t*>(bp + 2 * NCLS)[lane];
        f32x4_t v3 = reinterpret_cast<const f32x4_t*>(bp + 3 * NCLS)[lane];

        #define ROW(vk, k)                                                  \
        {                                                                   \
            const int t = targets[rbase + (k)];       /* wave-uniform */    \
            const float2 c = ab[t];                                         \
            float zp = (__expf(vk.x) + __expf(vk.y))                        \
                     + (__expf(vk.z) + __expf(vk.w));                       \
            float z = red64(zp);                                            \
            accU += c.x + __logf(z);                                        \
            float db = fl4 - (float)t;                                      \
            float swxl = 0.0f;                                              \
            _Pragma("unroll")                                               \
            for (int j = 0; j < 4; ++j) {                                   \
                float d  = db + (float)j;                                   \
                float d2 = d * d;                                           \
                float a  = d2 * d2 * 0.02f;  /* exact 0 weight for |d|>8 */ \
                swxl = fmaf(__expf(-a), vk[j], swxl);                       \
            }                                                               \
            accW = fmaf(-c.y, swxl, accW);                                  \
        }

        ROW(v0, 0)
        ROW(v1, 1)
        ROW(v2, 2)
        ROW(v3, 3)
        #undef ROW
    }

    // accU is identical on all 64 lanes -> fold with 1/64 so the full-wave
    // reduce counts it exactly once.
    float acc = fmaf(accU, 1.0f / 64.0f, accW);
    acc = red64(acc);
    if (lane == 0) part[wib] = acc;
    __syncthreads();
    if (tid == 0) {
        float s = (part[0] + part[1] + part[2] + part[3]) / (float)batch;
        atomicAdd(out, s);
    }
}

extern "C" void kernel_launch(void* const* d_in, const int* in_sizes, int n_in,
                              void* d_out, int out_size, void* d_ws, size_t ws_size,
                              hipStream_t stream) {
    const float* logits  = (const float*)d_in[0];
    const int*   targets = (const int*)d_in[1];
    float*       out     = (float*)d_out;
    const int batch = in_sizes[1];           // 262144

    hipMemsetAsync(d_out, 0, sizeof(float), stream);

    dim3 block(256);
    dim3 grid(2048);                         // 8192 waves, 8 chunks (32 rows) each
    SmoothOrdinalLoss_kernel<<<grid, block, 0, stream>>>(logits, targets, out, batch);
}

// Round 6
// 46.676 us; speedup vs baseline: 1.3168x; 1.3168x over previous
//
#include <hip/hip_runtime.h>

#define NCLS 256

typedef float f32x4_t __attribute__((ext_vector_type(4)));

// DPP partial-sum helpers (verified rounds 2-5).
#define DPP_ADD(x, ctrl) \
    ((x) + __int_as_float(__builtin_amdgcn_update_dpp( \
        0, __float_as_int(x), (ctrl), 0xF, 0xF, true)))

__device__ __forceinline__ float red16(float x) {
    x = DPP_ADD(x, 0xB1);   // quad_perm xor1
    x = DPP_ADD(x, 0x4E);   // quad_perm xor2
    x = DPP_ADD(x, 0x141);  // row_half_mirror
    x = DPP_ADD(x, 0x140);  // row_mirror
    return x;
}

__device__ __forceinline__ float red64(float x) {
    x = red16(x);
    x += __shfl_xor(x, 16);
    x += __shfl_xor(x, 32);
    return x;               // all lanes hold the wave sum
}

// Per-row closed form (no max-subtraction; logits ~ N(0,1) so exp is safe):
//   lrow = A[t] + log(sum_c exp(x_c)) - swx * invS[t]
// A[t], invS[t]: t-only -> LDS table. swx*invS is LINEAR in lane partials ->
// accumulate per-lane (accW), reduce ONCE at wave end; only z gets a per-chunk
// red16. Weight gather: 512-entry zero-padded table, per-chunk base index
// idx0 = 4*li + 256 - t; the 16 reads use compile-time offsets 64k+j
// (range check: idx0 in [1,316], +195 max -> [1,511], always in bounds).
// No memset / no atomics: block partial -> plain store to ws[bid];
// reduce_kernel folds 2048 partials and writes out.
__global__ __launch_bounds__(256) void SmoothOrdinalLoss_main(
    const float* __restrict__ logits,
    const int* __restrict__ targets,
    float* __restrict__ ws,
    int batch)
{
    __shared__ float  wtab[512];
    __shared__ float2 ab[NCLS];
    __shared__ float  part[4];

    const int tid = threadIdx.x;

    // ---- build tables (once per block; no write races) ----
    {
        #pragma unroll
        for (int h = 0; h < 2; ++h) {
            int idx = tid + 256 * h;
            int d   = idx - 256;
            float w = 0.0f;
            if (d >= -8 && d <= 8) {
                float fd = (float)d;
                w = __expf(-(fd * fd) * (fd * fd) * 0.02f);  // exp(-d^4/50)
            }
            wtab[idx] = w;
        }
        const int t = tid;
        float sw = 0.0f, swlw = 0.0f;
        #pragma unroll
        for (int d = -8; d <= 8; ++d) {
            int c = t + d;
            if (c >= 0 && c < NCLS) {
                float fd = (float)d;
                float a  = (fd * fd) * (fd * fd) * 0.02f;
                float w  = __expf(-a);
                sw += w;
                swlw = fmaf(w, -a, swlw);                    // w * log w
            }
        }
        float invS = 1.0f / sw;
        ab[t] = make_float2(fmaf(swlw, invS, -__logf(sw)), invS);
    }
    __syncthreads();

    const int lane = tid & 63;
    const int wib  = tid >> 6;
    const int g    = lane >> 4;   // row within the wave's 4-row chunk
    const int li   = lane & 15;   // lane within the 16-lane row group

    const int wave    = blockIdx.x * 4 + wib;
    const int nwaves  = gridDim.x * 4;
    const int nchunks = batch >> 2;          // 4 rows per chunk

    float accU = 0.0f;   // sum over rows of A[t] + log z (replicated x16)
    float accW = 0.0f;   // per-lane partial of sum swx*invS

    const int li4 = li * 4;

    for (int ch = wave; ch < nchunks; ch += nwaves) {
        const int row = ch * 4 + g;
        const f32x4_t* rp =
            reinterpret_cast<const f32x4_t*>(logits + (size_t)row * NCLS);
        // lane li owns classes {4*li + 64*k + j}; 16 lanes x 16 B contiguous.
        f32x4_t v0 = rp[li];
        f32x4_t v1 = rp[li + 16];
        f32x4_t v2 = rp[li + 32];
        f32x4_t v3 = rp[li + 48];
        const int t = targets[row];          // uniform within 16-group

        // softmax denominator partial (4 parallel chains)
        float z0 = (__expf(v0.x) + __expf(v0.y)) + (__expf(v0.z) + __expf(v0.w));
        float z1 = (__expf(v1.x) + __expf(v1.y)) + (__expf(v1.z) + __expf(v1.w));
        float z2 = (__expf(v2.x) + __expf(v2.y)) + (__expf(v2.z) + __expf(v2.w));
        float z3 = (__expf(v3.x) + __expf(v3.y)) + (__expf(v3.z) + __expf(v3.w));
        float z  = red16((z0 + z1) + (z2 + z3));

        // window term: single base + immediate-offset LDS reads
        const float* wp = &wtab[li4 + 256 - t];
        float xs[16] = {v0.x, v0.y, v0.z, v0.w,  v1.x, v1.y, v1.z, v1.w,
                        v2.x, v2.y, v2.z, v2.w,  v3.x, v3.y, v3.z, v3.w};
        float swxl = 0.0f;
        #pragma unroll
        for (int k = 0; k < 4; ++k) {
            #pragma unroll
            for (int j = 0; j < 4; ++j)
                swxl = fmaf(wp[64 * k + j], xs[k * 4 + j], swxl);
        }

        float2 c = ab[t];
        accU += c.x + __logf(z);
        accW  = fmaf(swxl, c.y, accW);
    }

    // accU replicated within each 16-group -> fold 1/16; accW per-lane.
    float acc = red64(fmaf(accU, 0.0625f, -accW));
    if (lane == 0) part[wib] = acc;
    __syncthreads();
    if (tid == 0)
        ws[blockIdx.x] = (part[0] + part[1]) + (part[2] + part[3]);
}

__global__ __launch_bounds__(256) void SmoothOrdinalLoss_reduce(
    const float* __restrict__ ws,
    float* __restrict__ out,
    int nparts, float invB)
{
    __shared__ float part[4];
    const int tid = threadIdx.x;
    float s = 0.0f;
    for (int i = tid; i < nparts; i += 256) s += ws[i];
    s = red64(s);
    const int lane = tid & 63, wib = tid >> 6;
    if (lane == 0) part[wib] = s;
    __syncthreads();
    if (tid == 0)
        out[0] = ((part[0] + part[1]) + (part[2] + part[3])) * invB;
}

extern "C" void kernel_launch(void* const* d_in, const int* in_sizes, int n_in,
                              void* d_out, int out_size, void* d_ws, size_t ws_size,
                              hipStream_t stream) {
    const float* logits  = (const float*)d_in[0];
    const int*   targets = (const int*)d_in[1];
    float*       out     = (float*)d_out;
    float*       ws      = (float*)d_ws;
    const int batch = in_sizes[1];           // 262144

    const int nblocks = 2048;                // 8192 waves, 8 chunks each
    SmoothOrdinalLoss_main<<<dim3(nblocks), dim3(256), 0, stream>>>(
        logits, targets, ws, batch);
    SmoothOrdinalLoss_reduce<<<dim3(1), dim3(256), 0, stream>>>(
        ws, out, nblocks, 1.0f / (float)batch);
}